// Round 1
// baseline (486.009 us; speedup 1.0000x reference)
//
#include <hip/hip_runtime.h>
#include <hip/hip_cooperative_groups.h>
#include <stdint.h>
#include <stddef.h>

typedef __attribute__((ext_vector_type(8))) short short8;
typedef __attribute__((ext_vector_type(4))) float floatx4;
typedef __attribute__((ext_vector_type(2))) float floatx2;
typedef __attribute__((ext_vector_type(2))) unsigned int uintx2;
typedef __attribute__((ext_vector_type(4))) unsigned int uintx4;
typedef __attribute__((ext_vector_type(4))) int intx4;

#define HW_IN   4096       // 64*64
#define HW_GO   3844       // 62*62
#define OUT_ELEMS 294912   // 256*128*9
#define NCHUNK 64          // (n, half-of-i) chunks: z = n*2 + half
#define UNITS  31

// ws layout (bytes):
//   [0, 75497472)            : fp32 partials, 64 chunks x OUT_ELEMS
//   [75497472, 140509184)    : GO_ws bf16 [n][i][o=256][64], 16B chunks
//                              XOR-swizzled within each 128B row by (o&7),
//                              cols 62,63 zero
//   [140509184, 174063616)   : X_ws bf16 [n][c=128][h=64][w=64], 16B chunks
//                              XOR-swizzled within each 128B row by (c&7)
#define PART_BYTES   75497472ull
#define GO_BYTES     65011712ull
#define X_BYTES      33554432ull
#define WS_FULL      (PART_BYTES + GO_BYTES + X_BYTES)
#define PART62_BYTES 73138176ull   // fallback: 62-chunk fp32 partials

__device__ __forceinline__ uint32_t pk_bf16(float a, float b) {
    uint32_t ua = __float_as_uint(a); ua += 0x7FFFu + ((ua >> 16) & 1u);
    uint32_t ub = __float_as_uint(b); ub += 0x7FFFu + ((ub >> 16) & 1u);
    return (ua >> 16) | (ub & 0xFFFF0000u);
}

__device__ __forceinline__ void load_lds16(const void* g, void* l) {
    // LDS dest = wave-uniform base + lane*16 (m104/m108); global side per-lane.
    __builtin_amdgcn_global_load_lds(
        (const __attribute__((address_space(1))) void*)g,
        (__attribute__((address_space(3))) void*)l, 16, 0, 0);
}

// ============== single cooperative kernel: prep -> GEMM -> reduce ==========
__global__ __launch_bounds__(256, 2) void conv_fused(
    const float* __restrict__ inp, const float* __restrict__ gout,
    uint32_t* __restrict__ go_ws_u, uintx4* __restrict__ x_ws4,
    float* __restrict__ part, floatx4* __restrict__ out4)
{
    __shared__ __align__(16) short GO_sh[2][128 * 64];  // 32768 B
    __shared__ __align__(16) short X_ring[4][32 * 64];  // 16384 B

    cooperative_groups::grid_group grid = cooperative_groups::this_grid();

    const int tid = threadIdx.x;
    const uint32_t bflat = (blockIdx.z * 4 + blockIdx.y) * 2 + blockIdx.x;
    const uint32_t gtid = (bflat << 8) | (uint32_t)tid;   // < 131072

    // ---------------- phase 1: fp32 -> bf16 staging ----------------
    // GO: 4,063,232 tasks = 31 per thread exactly. Task = one 16B chunk
    // (4 dwords = 8 bf16 cols) of a 64-short row, stored at slot q^(o&7).
#pragma unroll 2
    for (int it = 0; it < 31; ++it) {
        const uint32_t g = (uint32_t)it * 131072u + gtid;
        const uint32_t row = g >> 3, q = g & 7u;       // row = (n*62+i)*256+o
        const uint32_t o = row & 255u, nio = row >> 8;
        const uint32_t n = nio / 62u;
        const uint32_t i = nio - n * 62u;
        const float* s = gout + (size_t)(n * 256 + o) * HW_GO + i * 62 + q * 8;
        uint32_t d0, d1, d2, d3;
        if (q < 7u) {
            const floatx2 a = *(const floatx2*)(s);
            const floatx2 b = *(const floatx2*)(s + 2);
            const floatx2 c = *(const floatx2*)(s + 4);
            const floatx2 d = *(const floatx2*)(s + 6);
            d0 = pk_bf16(a.x, a.y); d1 = pk_bf16(b.x, b.y);
            d2 = pk_bf16(c.x, c.y); d3 = pk_bf16(d.x, d.y);
        } else {  // floats 56..61 real, cols 62,63 zero (K padding)
            const floatx2 a = *(const floatx2*)(s);
            const floatx2 b = *(const floatx2*)(s + 2);
            const floatx2 c = *(const floatx2*)(s + 4);
            d0 = pk_bf16(a.x, a.y); d1 = pk_bf16(b.x, b.y);
            d2 = pk_bf16(c.x, c.y); d3 = 0u;
        }
        uintx4 v; v.x = d0; v.y = d1; v.z = d2; v.w = d3;
        *(uintx4*)(go_ws_u + (size_t)row * 32 + ((q ^ (o & 7u)) << 2)) = v;
    }
    // X: 2,097,152 tasks = 16 per thread exactly. Task = one 16B chunk,
    // swizzled by c&7 (t2>>9 == n*128+c).
    const floatx4* inp4 = (const floatx4*)inp;
#pragma unroll 2
    for (int it = 0; it < 16; ++it) {
        const uint32_t t2 = (uint32_t)it * 131072u + gtid;
        const floatx4 v0 = inp4[(size_t)t2 * 2];
        const floatx4 v1 = inp4[(size_t)t2 * 2 + 1];
        const uint32_t phys = (t2 & ~7u) | ((t2 & 7u) ^ ((t2 >> 9) & 7u));
        uintx4 w;
        w.x = pk_bf16(v0.x, v0.y); w.y = pk_bf16(v0.z, v0.w);
        w.z = pk_bf16(v1.x, v1.y); w.w = pk_bf16(v1.z, v1.w);
        x_ws4[phys] = w;
    }

    grid.sync();

    // ---------------- phase 2: per-chunk partial GEMM ----------------
    const int lane = tid & 63;
    const int wave = tid >> 6;
    const int l15  = lane & 15;
    const int quad = lane >> 4;

    const int Mbase = blockIdx.x * 128;    // 0,128
    const int Cbase = blockIdx.y * 32;     // 0..96
    const int nimg  = blockIdx.z >> 1;     // image n
    const int i0    = (blockIdx.z & 1) * 31;  // i in [i0, i0+31)

    const short* go_b = (const short*)go_ws_u + ((size_t)(nimg * 62) << 14);
    const short* x_b  = (const short*)x_ws4 + ((size_t)(nimg * 128 + Cbase) << 12);

    const int xlane_off = ((lane >> 3) << 12) + ((lane & 7) << 3);
    const int glane_off = lane << 3;

    floatx4 acc[2][2][9];
#pragma unroll
    for (int mi = 0; mi < 2; ++mi)
#pragma unroll
        for (int ni = 0; ni < 2; ++ni)
#pragma unroll
            for (int t = 0; t < 9; ++t)
                acc[mi][ni][t] = (floatx4){0.f, 0.f, 0.f, 0.f};

    // prologue: GO(i0) -> buf0; X rows i0..i0+2 -> ring slots
    {
        const short* gsrc = go_b + ((size_t)i0 << 14) + (Mbase << 6);
#pragma unroll
        for (int k = wave; k < 16; k += 4)
            load_lds16(gsrc + k * 512 + glane_off, &GO_sh[0][k * 512]);
#pragma unroll
        for (int m = 0; m < 3; ++m) {
            const int h = i0 + m;
            load_lds16(x_b + ((size_t)wave << 15) + (h << 6) + xlane_off,
                       &X_ring[h & 3][wave * 512]);
        }
    }

#pragma unroll 1
    for (int uu = 0; uu < UNITS; ++uu) {
        const int i = i0 + uu;
        __syncthreads();   // drains prev-issued DMA; protects ring slot reuse

        if (uu + 1 < UNITS) {
            // GO(i+1) -> other buf (4 loads/wave)
            const short* gsrc = go_b + ((size_t)(i + 1) << 14) + (Mbase << 6);
            short* gdst = &GO_sh[(uu + 1) & 1][0];
#pragma unroll
            for (int k = wave; k < 16; k += 4)
                load_lds16(gsrc + k * 512 + glane_off, gdst + k * 512);
            // X row i+3 -> ring slot (i+3)&3 (1 load/wave)
            load_lds16(x_b + ((size_t)wave << 15) + ((i + 3) << 6) + xlane_off,
                       &X_ring[(i + 3) & 3][wave * 512]);
        }

        const short* Gb = &GO_sh[uu & 1][0];
        short8 a[2][2];
#pragma unroll
        for (int mi = 0; mi < 2; ++mi)
#pragma unroll
            for (int ks = 0; ks < 2; ++ks)
                a[mi][ks] = *(const short8*)(
                    Gb + ((wave * 32 + mi * 16 + l15) << 6)
                       + ((((ks << 2) | quad) ^ (l15 & 7)) << 3));

        const int r7 = l15 & 7;
#pragma unroll
        for (int kh = 0; kh < 3; ++kh) {
            const short* Xs = &X_ring[(i + kh) & 3][0];
#pragma unroll
            for (int ni = 0; ni < 2; ++ni) {
                const short* xrow = Xs + ((ni * 16 + l15) << 6);
#pragma unroll
                for (int ks = 0; ks < 2; ++ks) {
                    const int lc = ks * 4 + quad;
                    const intx4 d = *(const intx4*)(xrow + ((lc ^ r7) << 3));
                    const int d4 =
                        *(const int*)(xrow + ((((lc + 1) & 7) ^ r7) << 3));
                    const uint32_t e0 = (uint32_t)d.x, e1 = (uint32_t)d.y,
                                   e2 = (uint32_t)d.z, e3 = (uint32_t)d.w,
                                   e4 = (uint32_t)d4;
                    union { uint32_t u[4]; short8 s; } f0, f1, f2;
                    f0.u[0] = e0; f0.u[1] = e1; f0.u[2] = e2; f0.u[3] = e3;
                    f1.u[0] = (e0 >> 16) | (e1 << 16);
                    f1.u[1] = (e1 >> 16) | (e2 << 16);
                    f1.u[2] = (e2 >> 16) | (e3 << 16);
                    f1.u[3] = (e3 >> 16) | (e4 << 16);
                    f2.u[0] = e1; f2.u[1] = e2; f2.u[2] = e3; f2.u[3] = e4;
#pragma unroll
                    for (int mi = 0; mi < 2; ++mi) {
                        acc[mi][ni][kh * 3 + 0] =
                            __builtin_amdgcn_mfma_f32_16x16x32_bf16(
                                a[mi][ks], f0.s, acc[mi][ni][kh * 3 + 0], 0, 0, 0);
                        acc[mi][ni][kh * 3 + 1] =
                            __builtin_amdgcn_mfma_f32_16x16x32_bf16(
                                a[mi][ks], f1.s, acc[mi][ni][kh * 3 + 1], 0, 0, 0);
                        acc[mi][ni][kh * 3 + 2] =
                            __builtin_amdgcn_mfma_f32_16x16x32_bf16(
                                a[mi][ks], f2.s, acc[mi][ni][kh * 3 + 2], 0, 0, 0);
                    }
                }
            }
        }
    }

    // epilogue: C/D layout col=lane&15, row=quad*4+reg (m89/m91)
    {
        float* baseo = part + (size_t)blockIdx.z * OUT_ELEMS;
#pragma unroll
        for (int mi = 0; mi < 2; ++mi) {
            const int o_base = Mbase + wave * 32 + mi * 16 + quad * 4;
#pragma unroll
            for (int ni = 0; ni < 2; ++ni) {
                const int c = Cbase + ni * 16 + l15;
#pragma unroll
                for (int t = 0; t < 9; ++t)
#pragma unroll
                    for (int r = 0; r < 4; ++r)
                        baseo[(size_t)(o_base + r) * 1152 + c * 9 + t] =
                            acc[mi][ni][t][r];
            }
        }
    }

    grid.sync();

    // ---------------- phase 3: reduce 64 chunks ----------------
    if (gtid < OUT_ELEMS / 4) {
        const floatx4* p4 = (const floatx4*)part;
        floatx4 s = {0.f, 0.f, 0.f, 0.f};
#pragma unroll 8
        for (int ch = 0; ch < NCHUNK; ++ch)
            s += p4[(size_t)ch * (OUT_ELEMS / 4) + gtid];
        out4[gtid] = s;
    }
}

// ================= fallback (fp32 direct, self-contained) =================
template<bool USE_ATOMIC>
__global__ __launch_bounds__(256, 1) void convbw_kernel(
    const float* __restrict__ inp, const float* __restrict__ gout,
    float* __restrict__ dst)
{
    __shared__ __align__(16) short GO_sh[128][72];
    __shared__ __align__(16) short X_sh[3][3][32][72];
    const int tid = threadIdx.x, lane = tid & 63, wave = tid >> 6;
    const int l15 = lane & 15, quad = lane >> 4;
    const int Mbase = blockIdx.x * 128, Cbase = blockIdx.y * 32;
    const int chunk = blockIdx.z;
    const int gl = tid & 31, grow0 = tid >> 5, xl = tid & 15, xrow0 = tid >> 4;
    floatx2 go_r[16];
    floatx4 x_r[6];
    auto issue_loads = [&](int u) {
        const int n_img = u / 62, i = u - n_img * 62;
        const float* bg = gout + (size_t)(n_img * 256 + Mbase) * HW_GO + i * 62;
        const float* bi = inp + (size_t)(n_img * 128 + Cbase) * HW_IN + i * 64;
#pragma unroll
        for (int p = 0; p < 16; ++p)
            go_r[p] = *(const floatx2*)(bg + (size_t)(grow0 + p * 8) * HW_GO + gl * 2);
#pragma unroll
        for (int p = 0; p < 6; ++p) {
            const int row = xrow0 + p * 16, c = row & 31, kh = row >> 5;
            x_r[p] = *(const floatx4*)(bi + (size_t)c * HW_IN + kh * 64 + xl * 4);
        }
    };
    auto flush = [&]() {
#pragma unroll
        for (int p = 0; p < 16; ++p) {
            uint32_t v = pk_bf16(go_r[p].x, go_r[p].y);
            if (gl == 31) v = 0;
            *(uint32_t*)&GO_sh[grow0 + p * 8][gl * 2] = v;
        }
#pragma unroll
        for (int p = 0; p < 6; ++p) {
            const int row = xrow0 + p * 16, c = row & 31, kh = row >> 5;
            uint32_t lo = pk_bf16(x_r[p].x, x_r[p].y);
            uint32_t hi = pk_bf16(x_r[p].z, x_r[p].w);
            uint32_t nlo = (uint32_t)__shfl((int)lo, (lane + 1) & 63);
            uintx2 v0 = {lo, hi};
            uintx2 v1 = {(lo >> 16) | (hi << 16), (hi >> 16) | (nlo << 16)};
            uintx2 v2 = {hi, nlo};
            *(uintx2*)&X_sh[kh][0][c][xl * 4] = v0;
            *(uintx2*)&X_sh[kh][1][c][xl * 4] = v1;
            *(uintx2*)&X_sh[kh][2][c][xl * 4] = v2;
        }
    };
    floatx4 acc[2][2][9];
#pragma unroll
    for (int mi = 0; mi < 2; ++mi)
#pragma unroll
        for (int ni = 0; ni < 2; ++ni)
#pragma unroll
            for (int t = 0; t < 9; ++t) acc[mi][ni][t] = (floatx4){0,0,0,0};
    issue_loads(chunk * 32);
#pragma unroll 1
    for (int uu = 0; uu < 32; ++uu) {
        flush();
        if (uu + 1 < 32) issue_loads(chunk * 32 + uu + 1);
        __syncthreads();
#pragma unroll
        for (int ks = 0; ks < 2; ++ks) {
            const int kc = ks * 32 + quad * 8;
            const short8 a0 = *(const short8*)&GO_sh[wave * 32 + l15][kc];
            const short8 a1 = *(const short8*)&GO_sh[wave * 32 + 16 + l15][kc];
#pragma unroll
            for (int kh = 0; kh < 3; ++kh)
#pragma unroll
                for (int kw = 0; kw < 3; ++kw) {
                    const int t = kh * 3 + kw;
#pragma unroll
                    for (int ni = 0; ni < 2; ++ni) {
                        const short8 b = *(const short8*)&X_sh[kh][kw][ni * 16 + l15][kc];
                        acc[0][ni][t] = __builtin_amdgcn_mfma_f32_16x16x32_bf16(a0, b, acc[0][ni][t], 0, 0, 0);
                        acc[1][ni][t] = __builtin_amdgcn_mfma_f32_16x16x32_bf16(a1, b, acc[1][ni][t], 0, 0, 0);
                    }
                }
        }
        __syncthreads();
    }
    float* base = USE_ATOMIC ? dst : dst + (size_t)chunk * OUT_ELEMS;
#pragma unroll
    for (int mi = 0; mi < 2; ++mi) {
        const int o_base = Mbase + wave * 32 + mi * 16 + quad * 4;
#pragma unroll
        for (int ni = 0; ni < 2; ++ni) {
            const int c = Cbase + ni * 16 + l15;
#pragma unroll
            for (int t = 0; t < 9; ++t)
#pragma unroll
                for (int r = 0; r < 4; ++r) {
                    const size_t off = (size_t)(o_base + r) * 1152 + c * 9 + t;
                    if (USE_ATOMIC) atomicAdd(base + off, acc[mi][ni][t][r]);
                    else base[off] = acc[mi][ni][t][r];
                }
        }
    }
}

__global__ __launch_bounds__(256) void reduce_kernel(
    const floatx4* __restrict__ ws, floatx4* __restrict__ out, int nchunk)
{
    const int idx = blockIdx.x * 256 + threadIdx.x;
    floatx4 s = {0.f, 0.f, 0.f, 0.f};
#pragma unroll 2
    for (int ch = 0; ch < nchunk; ++ch)
        s += ws[(size_t)ch * (OUT_ELEMS / 4) + idx];
    out[idx] = s;
}

extern "C" void kernel_launch(void* const* d_in, const int* in_sizes, int n_in,
                              void* d_out, int out_size, void* d_ws, size_t ws_size,
                              hipStream_t stream) {
    const float* inp  = (const float*)d_in[0];
    const float* gout = (const float*)d_in[1];

    if (ws_size >= WS_FULL) {
        float* part = (float*)d_ws;
        uint32_t* go_ws_u = (uint32_t*)((char*)d_ws + PART_BYTES);
        uintx4* x_ws4 = (uintx4*)((char*)d_ws + PART_BYTES + GO_BYTES);
        floatx4* out4 = (floatx4*)d_out;
        void* args[6] = { (void*)&inp, (void*)&gout, (void*)&go_ws_u,
                          (void*)&x_ws4, (void*)&part, (void*)&out4 };
        hipError_t e = hipLaunchCooperativeKernel(
            reinterpret_cast<const void*>(&conv_fused),
            dim3(2, 4, NCHUNK), dim3(256, 1, 1), args, 0, stream);
        if (e == hipSuccess) return;
        (void)hipGetLastError();   // clear sticky error; fall through
    }
    // fallback: fp32-direct path (no bf16 staging buffers needed)
    dim3 grid(2, 4, 62);
    if (ws_size >= PART62_BYTES) {
        float* part = (float*)d_ws;
        convbw_kernel<false><<<grid, 256, 0, stream>>>(inp, gout, part);
        reduce_kernel<<<OUT_ELEMS / 4 / 256, 256, 0, stream>>>(
            (const floatx4*)part, (floatx4*)d_out, 62);
    } else {
        hipMemsetAsync(d_out, 0, (size_t)out_size * sizeof(float), stream);
        convbw_kernel<true><<<grid, 256, 0, stream>>>(inp, gout, (float*)d_out);
    }
}

// Round 2
// 331.295 us; speedup vs baseline: 1.4670x; 1.4670x over previous
//
#include <hip/hip_runtime.h>
#include <stdint.h>
#include <stddef.h>

typedef __attribute__((ext_vector_type(8))) short short8;
typedef __attribute__((ext_vector_type(4))) float floatx4;
typedef __attribute__((ext_vector_type(2))) float floatx2;
typedef __attribute__((ext_vector_type(2))) unsigned int uintx2;
typedef __attribute__((ext_vector_type(4))) unsigned int uintx4;
typedef __attribute__((ext_vector_type(4))) int intx4;

#define HW_IN   4096       // 64*64
#define HW_GO   3844       // 62*62
#define OUT_ELEMS 294912   // 256*128*9
#define NCHUNK 64          // (n, half-of-i): z = n*2 + half
#define UNITS  31

// ws layout (bytes):
//   [0, 75497472)          : fp32 partials, 64 chunks x OUT_ELEMS
//   [75497472, 140509184)  : GO_ws bf16 [n][i][o=256][64], 16B chunks
//                            XOR-swizzled within each 128B row by (o&7),
//                            cols 62,63 zero
//   [140509184, 174063616) : X_ws bf16 [n][c=128][h=64][w=64], 16B chunks
//                            XOR-swizzled within each 128B row by (c&7)
#define PART_BYTES   75497472ull
#define GO_BYTES     65011712ull
#define X_BYTES      33554432ull
#define WS_FULL      (PART_BYTES + GO_BYTES + X_BYTES)
#define PART62_BYTES 73138176ull   // fallback: 62-chunk fp32 partials

#define GO_THREADS 1015808u   // 4,063,232 GO chunk-tasks / 4
#define GO_BLOCKS  3968
#define X_THREADS  524288u    // 2,097,152 X chunk-tasks / 4
#define X_BLOCKS   2048

__device__ __forceinline__ uint32_t pk_bf16(float a, float b) {
    uint32_t ua = __float_as_uint(a); ua += 0x7FFFu + ((ua >> 16) & 1u);
    uint32_t ub = __float_as_uint(b); ub += 0x7FFFu + ((ub >> 16) & 1u);
    return (ua >> 16) | (ub & 0xFFFF0000u);
}

__device__ __forceinline__ void load_lds16(const void* g, void* l) {
    // LDS dest = wave-uniform base + lane*16 (m104/m108); global side per-lane.
    __builtin_amdgcn_global_load_lds(
        (const __attribute__((address_space(1))) void*)g,
        (__attribute__((address_space(3))) void*)l, 16, 0, 0);
}

// ---- prep: both fp32->bf16 conversions in one launch, 16B-chunk tasks ----
__global__ __launch_bounds__(256) void prep_kernel(
    const float* __restrict__ gout, const float* __restrict__ inp,
    uintx4* __restrict__ go_ws4, uintx4* __restrict__ x_ws4)
{
    const uint32_t b = blockIdx.x;
    if (b < GO_BLOCKS) {
        const uint32_t t0 = b * 256u + threadIdx.x;
#pragma unroll
        for (int it = 0; it < 4; ++it) {
            const uint32_t g = t0 + (uint32_t)it * GO_THREADS;
            const uint32_t row = g >> 3, q = g & 7u;   // row=(n*62+i)*256+o
            const uint32_t o = row & 255u, nio = row >> 8;
            const uint32_t n = nio / 62u, i = nio - n * 62u;
            const float* s = gout + (size_t)(n * 256u + o) * HW_GO
                                  + i * 62u + q * 8u;
            const floatx2 a0 = *(const floatx2*)(s);
            const floatx2 a1 = *(const floatx2*)(s + 2);
            const floatx2 a2 = *(const floatx2*)(s + 4);
            uintx4 v;
            v.x = pk_bf16(a0.x, a0.y);
            v.y = pk_bf16(a1.x, a1.y);
            v.z = pk_bf16(a2.x, a2.y);
            if (q < 7u) {                 // cols 62,63 stay zero (K padding)
                const floatx2 a3 = *(const floatx2*)(s + 6);
                v.w = pk_bf16(a3.x, a3.y);
            } else v.w = 0u;
            go_ws4[(size_t)row * 8u + (q ^ (o & 7u))] = v;
        }
    } else {
        const uint32_t t0 = (b - GO_BLOCKS) * 256u + threadIdx.x;
        const floatx4* inp4 = (const floatx4*)inp;
#pragma unroll
        for (int it = 0; it < 4; ++it) {
            const uint32_t t2 = t0 + (uint32_t)it * X_THREADS;
            const floatx4 v0 = inp4[(size_t)t2 * 2];
            const floatx4 v1 = inp4[(size_t)t2 * 2 + 1];
            const uint32_t phys = (t2 & ~7u) | ((t2 & 7u) ^ ((t2 >> 9) & 7u));
            uintx4 w;
            w.x = pk_bf16(v0.x, v0.y); w.y = pk_bf16(v0.z, v0.w);
            w.z = pk_bf16(v1.x, v1.y); w.w = pk_bf16(v1.z, v1.w);
            x_ws4[phys] = w;
        }
    }
}

// ---- main GEMM: counted-vmcnt pipeline (T3/T4), GO 3-buf, X 8-ring ----
__global__ __launch_bounds__(256, 2) void convbw3_kernel(
    const short* __restrict__ go_ws,   // [n][i][256][64] bf16, swizzled
    const short* __restrict__ x_ws,    // [n][128][64][64] bf16, swizzled
    float* __restrict__ part)          // partials, chunk-major
{
    __shared__ __align__(16) short GO_sh[3][128 * 64];  // 49152 B
    __shared__ __align__(16) short X_ring[8][32 * 64];  // 32768 B  (80KB tot)

    const int tid  = threadIdx.x;
    const int lane = tid & 63;
    const int wave = tid >> 6;
    const int l15  = lane & 15;
    const int quad = lane >> 4;

    const int Mbase = blockIdx.x * 128;       // 0,128
    const int Cbase = blockIdx.y * 32;        // 0..96
    const int nimg  = blockIdx.z >> 1;        // image
    const int i0    = (blockIdx.z & 1) * 31;  // i in [i0, i0+31)

    const short* go_b = go_ws + ((size_t)(nimg * 62) << 14);
    const short* x_b  = x_ws + ((size_t)(nimg * 128 + Cbase) << 12);

    const int xlane_off = ((lane >> 3) << 12) + ((lane & 7) << 3);
    const int glane_off = lane << 3;

    // per-wave DMA: 4 GO loads + 1 X load per unit => counted vmcnt(5)
    auto issue_go = [&](int u, int buf) {
        const short* gsrc = go_b + ((size_t)(i0 + u) << 14) + (Mbase << 6);
        short* gdst = &GO_sh[buf][0];
#pragma unroll
        for (int k = wave; k < 16; k += 4)
            load_lds16(gsrc + k * 512 + glane_off, gdst + k * 512);
    };
    auto issue_x = [&](int h) {   // absolute input row h, slot h&7
        load_lds16(x_b + ((size_t)wave << 15) + (h << 6) + xlane_off,
                   &X_ring[h & 7][wave * 512]);
    };

    floatx4 acc[2][2][9];
#pragma unroll
    for (int mi = 0; mi < 2; ++mi)
#pragma unroll
        for (int ni = 0; ni < 2; ++ni)
#pragma unroll
            for (int t = 0; t < 9; ++t)
                acc[mi][ni][t] = (floatx4){0.f, 0.f, 0.f, 0.f};

    // prologue: units 0 and 1 in flight (7 + 5 loads per wave)
    issue_go(0, 0);
    issue_x(i0); issue_x(i0 + 1); issue_x(i0 + 2);
    issue_go(1, 1);
    issue_x(i0 + 3);

    int bcur = 0;
#pragma unroll 1
    for (int uu = 0; uu < UNITS; ++uu) {
        const int i = i0 + uu;
        // wait for unit uu's own loads (newest 5 = unit uu+1's may fly on)
        if (uu < UNITS - 1) asm volatile("s_waitcnt vmcnt(5)" ::: "memory");
        else                asm volatile("s_waitcnt vmcnt(0)" ::: "memory");
        __builtin_amdgcn_s_barrier();
        asm volatile("" ::: "memory");

        if (uu + 2 < UNITS) {     // issue unit uu+2, two barriers ahead
            int b2 = bcur + 2; if (b2 >= 3) b2 -= 3;
            issue_go(uu + 2, b2);
            issue_x(i + 4);
        }

        const short* Gb = &GO_sh[bcur][0];
        short8 a[2][2];
#pragma unroll
        for (int mi = 0; mi < 2; ++mi)
#pragma unroll
            for (int ks = 0; ks < 2; ++ks)
                a[mi][ks] = *(const short8*)(
                    Gb + ((wave * 32 + mi * 16 + l15) << 6)
                       + ((((ks << 2) | quad) ^ (l15 & 7)) << 3));

        const int r7 = l15 & 7;
#pragma unroll
        for (int kh = 0; kh < 3; ++kh) {
            const short* Xs = &X_ring[(i + kh) & 7][0];
#pragma unroll
            for (int ni = 0; ni < 2; ++ni) {
                const short* xrow = Xs + ((ni * 16 + l15) << 6);
#pragma unroll
                for (int ks = 0; ks < 2; ++ks) {
                    const int lc = ks * 4 + quad;
                    const intx4 d = *(const intx4*)(xrow + ((lc ^ r7) << 3));
                    const int d4 =
                        *(const int*)(xrow + ((((lc + 1) & 7) ^ r7) << 3));
                    const uint32_t e0 = (uint32_t)d.x, e1 = (uint32_t)d.y,
                                   e2 = (uint32_t)d.z, e3 = (uint32_t)d.w,
                                   e4 = (uint32_t)d4;
                    union { uint32_t u[4]; short8 s; } f0, f1, f2;
                    f0.u[0] = e0; f0.u[1] = e1; f0.u[2] = e2; f0.u[3] = e3;
                    f1.u[0] = (e0 >> 16) | (e1 << 16);
                    f1.u[1] = (e1 >> 16) | (e2 << 16);
                    f1.u[2] = (e2 >> 16) | (e3 << 16);
                    f1.u[3] = (e3 >> 16) | (e4 << 16);
                    f2.u[0] = e1; f2.u[1] = e2; f2.u[2] = e3; f2.u[3] = e4;
#pragma unroll
                    for (int mi = 0; mi < 2; ++mi) {
                        acc[mi][ni][kh * 3 + 0] =
                            __builtin_amdgcn_mfma_f32_16x16x32_bf16(
                                a[mi][ks], f0.s, acc[mi][ni][kh * 3 + 0], 0, 0, 0);
                        acc[mi][ni][kh * 3 + 1] =
                            __builtin_amdgcn_mfma_f32_16x16x32_bf16(
                                a[mi][ks], f1.s, acc[mi][ni][kh * 3 + 1], 0, 0, 0);
                        acc[mi][ni][kh * 3 + 2] =
                            __builtin_amdgcn_mfma_f32_16x16x32_bf16(
                                a[mi][ks], f2.s, acc[mi][ni][kh * 3 + 2], 0, 0, 0);
                    }
                }
            }
        }
        bcur = (bcur == 2) ? 0 : bcur + 1;
    }

    // epilogue: C/D layout col=lane&15, row=quad*4+reg (m89/m91)
    float* baseo = part + (size_t)blockIdx.z * OUT_ELEMS;
#pragma unroll
    for (int mi = 0; mi < 2; ++mi) {
        const int o_base = Mbase + wave * 32 + mi * 16 + quad * 4;
#pragma unroll
        for (int ni = 0; ni < 2; ++ni) {
            const int c = Cbase + ni * 16 + l15;
#pragma unroll
            for (int t = 0; t < 9; ++t)
#pragma unroll
                for (int r = 0; r < 4; ++r)
                    baseo[(size_t)(o_base + r) * 1152 + c * 9 + t] =
                        acc[mi][ni][t][r];
        }
    }
}

__global__ __launch_bounds__(256) void reduce_kernel(
    const floatx4* __restrict__ ws, floatx4* __restrict__ out, int nchunk)
{
    const int idx = blockIdx.x * 256 + threadIdx.x;
    floatx4 s = {0.f, 0.f, 0.f, 0.f};
#pragma unroll 4
    for (int ch = 0; ch < nchunk; ++ch)
        s += ws[(size_t)ch * (OUT_ELEMS / 4) + idx];
    out[idx] = s;
}

// ================= fallback (fp32 direct, self-contained) =================
template<bool USE_ATOMIC>
__global__ __launch_bounds__(256, 1) void convbw_kernel(
    const float* __restrict__ inp, const float* __restrict__ gout,
    float* __restrict__ dst)
{
    __shared__ __align__(16) short GO_sh[128][72];
    __shared__ __align__(16) short X_sh[3][3][32][72];
    const int tid = threadIdx.x, lane = tid & 63, wave = tid >> 6;
    const int l15 = lane & 15, quad = lane >> 4;
    const int Mbase = blockIdx.x * 128, Cbase = blockIdx.y * 32;
    const int chunk = blockIdx.z;
    const int gl = tid & 31, grow0 = tid >> 5, xl = tid & 15, xrow0 = tid >> 4;
    floatx2 go_r[16];
    floatx4 x_r[6];
    auto issue_loads = [&](int u) {
        const int n_img = u / 62, i = u - n_img * 62;
        const float* bg = gout + (size_t)(n_img * 256 + Mbase) * HW_GO + i * 62;
        const float* bi = inp + (size_t)(n_img * 128 + Cbase) * HW_IN + i * 64;
#pragma unroll
        for (int p = 0; p < 16; ++p)
            go_r[p] = *(const floatx2*)(bg + (size_t)(grow0 + p * 8) * HW_GO + gl * 2);
#pragma unroll
        for (int p = 0; p < 6; ++p) {
            const int row = xrow0 + p * 16, c = row & 31, kh = row >> 5;
            x_r[p] = *(const floatx4*)(bi + (size_t)c * HW_IN + kh * 64 + xl * 4);
        }
    };
    auto flush = [&]() {
#pragma unroll
        for (int p = 0; p < 16; ++p) {
            uint32_t v = pk_bf16(go_r[p].x, go_r[p].y);
            if (gl == 31) v = 0;
            *(uint32_t*)&GO_sh[grow0 + p * 8][gl * 2] = v;
        }
#pragma unroll
        for (int p = 0; p < 6; ++p) {
            const int row = xrow0 + p * 16, c = row & 31, kh = row >> 5;
            uint32_t lo = pk_bf16(x_r[p].x, x_r[p].y);
            uint32_t hi = pk_bf16(x_r[p].z, x_r[p].w);
            uint32_t nlo = (uint32_t)__shfl((int)lo, (lane + 1) & 63);
            uintx2 v0 = {lo, hi};
            uintx2 v1 = {(lo >> 16) | (hi << 16), (hi >> 16) | (nlo << 16)};
            uintx2 v2 = {hi, nlo};
            *(uintx2*)&X_sh[kh][0][c][xl * 4] = v0;
            *(uintx2*)&X_sh[kh][1][c][xl * 4] = v1;
            *(uintx2*)&X_sh[kh][2][c][xl * 4] = v2;
        }
    };
    floatx4 acc[2][2][9];
#pragma unroll
    for (int mi = 0; mi < 2; ++mi)
#pragma unroll
        for (int ni = 0; ni < 2; ++ni)
#pragma unroll
            for (int t = 0; t < 9; ++t) acc[mi][ni][t] = (floatx4){0,0,0,0};
    issue_loads(chunk * 32);
#pragma unroll 1
    for (int uu = 0; uu < 32; ++uu) {
        flush();
        if (uu + 1 < 32) issue_loads(chunk * 32 + uu + 1);
        __syncthreads();
#pragma unroll
        for (int ks = 0; ks < 2; ++ks) {
            const int kc = ks * 32 + quad * 8;
            const short8 a0 = *(const short8*)&GO_sh[wave * 32 + l15][kc];
            const short8 a1 = *(const short8*)&GO_sh[wave * 32 + 16 + l15][kc];
#pragma unroll
            for (int kh = 0; kh < 3; ++kh)
#pragma unroll
                for (int kw = 0; kw < 3; ++kw) {
                    const int t = kh * 3 + kw;
#pragma unroll
                    for (int ni = 0; ni < 2; ++ni) {
                        const short8 b = *(const short8*)&X_sh[kh][kw][ni * 16 + l15][kc];
                        acc[0][ni][t] = __builtin_amdgcn_mfma_f32_16x16x32_bf16(a0, b, acc[0][ni][t], 0, 0, 0);
                        acc[1][ni][t] = __builtin_amdgcn_mfma_f32_16x16x32_bf16(a1, b, acc[1][ni][t], 0, 0, 0);
                    }
                }
        }
        __syncthreads();
    }
    float* base = USE_ATOMIC ? dst : dst + (size_t)chunk * OUT_ELEMS;
#pragma unroll
    for (int mi = 0; mi < 2; ++mi) {
        const int o_base = Mbase + wave * 32 + mi * 16 + quad * 4;
#pragma unroll
        for (int ni = 0; ni < 2; ++ni) {
            const int c = Cbase + ni * 16 + l15;
#pragma unroll
            for (int t = 0; t < 9; ++t)
#pragma unroll
                for (int r = 0; r < 4; ++r) {
                    const size_t off = (size_t)(o_base + r) * 1152 + c * 9 + t;
                    if (USE_ATOMIC) atomicAdd(base + off, acc[mi][ni][t][r]);
                    else base[off] = acc[mi][ni][t][r];
                }
        }
    }
}

extern "C" void kernel_launch(void* const* d_in, const int* in_sizes, int n_in,
                              void* d_out, int out_size, void* d_ws, size_t ws_size,
                              hipStream_t stream) {
    const float* inp  = (const float*)d_in[0];
    const float* gout = (const float*)d_in[1];

    if (ws_size >= WS_FULL) {
        float* part = (float*)d_ws;
        uintx4* go_ws4 = (uintx4*)((char*)d_ws + PART_BYTES);
        uintx4* x_ws4  = (uintx4*)((char*)d_ws + PART_BYTES + GO_BYTES);
        prep_kernel<<<GO_BLOCKS + X_BLOCKS, 256, 0, stream>>>(
            gout, inp, go_ws4, x_ws4);
        convbw3_kernel<<<dim3(2, 4, NCHUNK), 256, 0, stream>>>(
            (const short*)go_ws4, (const short*)x_ws4, part);
        reduce_kernel<<<OUT_ELEMS / 4 / 256, 256, 0, stream>>>(
            (const floatx4*)part, (floatx4*)d_out, NCHUNK);
        return;
    }
    // fallback: fp32-direct path (no bf16 staging buffers needed)
    dim3 grid(2, 4, 62);
    if (ws_size >= PART62_BYTES) {
        float* part = (float*)d_ws;
        convbw_kernel<false><<<grid, 256, 0, stream>>>(inp, gout, part);
        reduce_kernel<<<OUT_ELEMS / 4 / 256, 256, 0, stream>>>(
            (const floatx4*)part, (floatx4*)d_out, 62);
    } else {
        hipMemsetAsync(d_out, 0, (size_t)out_size * sizeof(float), stream);
        convbw_kernel<true><<<grid, 256, 0, stream>>>(inp, gout, (float*)d_out);
    }
}